// Round 5
// baseline (147.560 us; speedup 1.0000x reference)
//
#include <hip/hip_runtime.h>

#define LOG2E 1.4426950408889634f
#define LN2   0.6931471805599453

static constexpr int B  = 32;
static constexpr int T  = 1024;   // original time length; we use rows 0..1022
static constexpr int TT = 1023;   // T-1
static constexpr int V  = 1000;
static constexpr int L  = 256;    // padded target length; labels used are cols 1..255
static constexpr int S  = 511;    // 2*255+1 extended states (valid s: 0..510)
static constexpr int SP = 512;    // padded state stride (slot 511 == 0.0f)
static constexpr int TP = 1024;   // padded rows per batch in E

__device__ __forceinline__ float fexp2(float x) {
#if __has_builtin(__builtin_amdgcn_exp2f)
  return __builtin_amdgcn_exp2f(x);
#else
  return exp2f(x);
#endif
}
__device__ __forceinline__ float flog2(float x) {
#if __has_builtin(__builtin_amdgcn_logf)
  return __builtin_amdgcn_logf(x);   // v_log_f32 = log base 2
#else
  return log2f(x);
#endif
}

// ---- DPP helpers (VALU cross-lane; no LDS) ------------------------------
#if __has_builtin(__builtin_amdgcn_update_dpp)
// wave_shr1: lane i <- lane i-1; lane 0 <- 0 (bound_ctrl)
__device__ __forceinline__ float shr1f(float x) {
  int r = __builtin_amdgcn_update_dpp(0, __float_as_int(x), 0x138, 0xf, 0xf, true);
  return __int_as_float(r);
}
__device__ __forceinline__ int dppmax_step(int m, const int ctrl) {
  int t;
  switch (ctrl) {  // ctrl must be a literal per call site; switch keeps constants
    case 0x111: t = __builtin_amdgcn_update_dpp(0, m, 0x111, 0xf, 0xf, true); break;
    case 0x112: t = __builtin_amdgcn_update_dpp(0, m, 0x112, 0xf, 0xf, true); break;
    case 0x114: t = __builtin_amdgcn_update_dpp(0, m, 0x114, 0xf, 0xf, true); break;
    case 0x118: t = __builtin_amdgcn_update_dpp(0, m, 0x118, 0xf, 0xf, true); break;
    case 0x142: t = __builtin_amdgcn_update_dpp(0, m, 0x142, 0xf, 0xf, true); break;
    default:    t = __builtin_amdgcn_update_dpp(0, m, 0x143, 0xf, 0xf, true); break;
  }
  return max(m, t);
}
// wave-max of nonneg int across 64 lanes; result valid in lane 63
__device__ __forceinline__ int wavemax_to_sgpr(int m) {
  m = dppmax_step(m, 0x111);  // row_shr:1
  m = dppmax_step(m, 0x112);  // row_shr:2
  m = dppmax_step(m, 0x114);  // row_shr:4
  m = dppmax_step(m, 0x118);  // row_shr:8  -> lane15/31/47/63 = row max
  m = dppmax_step(m, 0x142);  // row_bcast15
  m = dppmax_step(m, 0x143);  // row_bcast31 -> lane63 = wave max
  return __builtin_amdgcn_readlane(m, 63);
}
#else
__device__ __forceinline__ float shr1f(float x) {
  float r = __shfl_up(x, 1, 64);
  return (threadIdx.x & 63) == 0 ? 0.0f : r;
}
__device__ __forceinline__ int wavemax_to_sgpr(int m) {
  for (int o = 32; o >= 1; o >>= 1) m = max(m, __shfl_xor(m, o, 64));
  return m;
}
#endif

// ---------------- K0: target lengths from padding mask -------------------
__global__ void k_tlen(const unsigned char* __restrict__ maskb,
                       int* __restrict__ tlen) {
  int b = blockIdx.x;
  int lane = threadIdx.x;
  int ca = 0;
  for (int k = lane; k < L; k += 64) ca += (maskb[b * L + k] != 0) ? 1 : 0;
  for (int o = 32; o >= 1; o >>= 1) ca += __shfl_xor(ca, o, 64);
  int cnt = ca;
  if (ca < 130) {  // wave-uniform: layout must be int32
    const int* mi = (const int*)maskb;
    int cb = 0;
    for (int k = lane; k < L; k += 64) cb += (mi[b * L + k] != 0) ? 1 : 0;
    for (int o = 32; o >= 1; o >>= 1) cb += __shfl_xor(cb, o, 64);
    cnt = cb;
  }
  if (lane == 0) tlen[b] = cnt - 1;
}

// ---------------- K1: fused softmax-scale + emit gather ------------------
// E[b][t][s] = 2^(y[ext_s] - rowmax) in f32 (<=1), 0 for invalid; slot 511 = 0.
// G[b][t] = rowmax - log2(sum 2^(y-rowmax))  (per-row log2 correction).
__global__ __launch_bounds__(256) void k_emit(const float* __restrict__ logits,
                                              const int* __restrict__ targets,
                                              const int* __restrict__ tlenp,
                                              float* __restrict__ E,
                                              float* __restrict__ G) {
  __shared__ float yrow[1000];
  __shared__ float smx[4];
  __shared__ float ssm[4];
  int bid = blockIdx.x;
  int b = bid / TT;
  int t = bid - b * TT;
  int tid = threadIdx.x;

  const float4* row = reinterpret_cast<const float4*>(logits + ((size_t)b * T + t) * V);
  float4 vv = make_float4(0.f, 0.f, 0.f, 0.f);
  float vmax = -3.402823466e38f;
  if (tid < 250) {  // 1000 = 250 * 4 exactly
    vv = row[tid];
    vv.x *= LOG2E; vv.y *= LOG2E; vv.z *= LOG2E; vv.w *= LOG2E;
    yrow[4 * tid + 0] = vv.x;
    yrow[4 * tid + 1] = vv.y;
    yrow[4 * tid + 2] = vv.z;
    yrow[4 * tid + 3] = vv.w;
    vmax = fmaxf(fmaxf(vv.x, vv.y), fmaxf(vv.z, vv.w));
  }
  for (int o = 32; o >= 1; o >>= 1) vmax = fmaxf(vmax, __shfl_xor(vmax, o, 64));
  int wid = tid >> 6;
  if ((tid & 63) == 0) smx[wid] = vmax;
  __syncthreads();
  float my = fmaxf(fmaxf(smx[0], smx[1]), fmaxf(smx[2], smx[3]));
  float ps = 0.0f;
  if (tid < 250) {
    ps = fexp2(vv.x - my) + fexp2(vv.y - my) + fexp2(vv.z - my) + fexp2(vv.w - my);
  }
  for (int o = 32; o >= 1; o >>= 1) ps += __shfl_xor(ps, o, 64);
  if ((tid & 63) == 0) ssm[wid] = ps;
  __syncthreads();
  float g = -flog2(ssm[0] + ssm[1] + ssm[2] + ssm[3]);  // = rowmax - lse2

  int tl = tlenp[b];
  int smax = 2 * tl + 1;  // valid: s < smax
  float* Erow = E + ((size_t)b * TP + t) * SP;
  if (tid < 128) {
    int s4 = tid << 2;               // s4, s4+1, s4+2, s4+3
    float eblank = fexp2(yrow[0] - my);
    int idx1 = (tid << 1) + 1;       // label index for s4+1
    int idx3 = (tid << 1) + 2;       // label index for s4+3
    bool last = (tid == 127);        // s4+3 == 511 (pad slot)
    if (last) idx3 = 0;              // keep targets access in-bounds
    float v1c = fexp2(yrow[targets[b * L + idx1]] - my);
    float v3c = fexp2(yrow[targets[b * L + idx3]] - my);
    float4 o;
    o.x = (s4     < smax) ? eblank : 0.0f;
    o.y = (s4 + 1 < smax) ? v1c    : 0.0f;
    o.z = (s4 + 2 < smax) ? eblank : 0.0f;
    o.w = (!last && (s4 + 3 < smax)) ? v3c : 0.0f;  // slot 511 -> 0
    reinterpret_cast<float4*>(Erow)[tid] = o;
    if (last) G[b * TT + t] = g;
  }
}

// ---------------- K1b: per-batch sum of G --------------------------------
__global__ void k_gsum(const float* __restrict__ G, double* __restrict__ GS) {
  int b = blockIdx.x;
  int lane = threadIdx.x;
  double s = 0.0;
  for (int k = lane; k < TT; k += 64) s += (double)G[b * TT + k];
  for (int o = 32; o >= 1; o >>= 1) s += __shfl_xor(s, o, 64);
  if (lane == 0) GS[b] = s;
}

// ---------------- K2: CTC alpha recurrence, f32 prob domain --------------
// One wave per batch; lane l owns states 8l..8l+7. DPP wave_shr1 for the
// cross-lane state. 4-deep register prefetch (32 rows in flight, ~1400 cy
// of compute between load issue and use > ~900 cy HBM latency).
// Exact pow2 rescale (wave max -> 2^102) every 8 steps.
__global__ __launch_bounds__(64, 1) void k_ctc(const float* __restrict__ E,
                                               const int* __restrict__ targets,
                                               const int* __restrict__ tlenp,
                                               const double* __restrict__ GS,
                                               float* __restrict__ lossb) {
  const int b = blockIdx.x;
  const int lane = threadIdx.x;
  const int s0 = lane << 3;
  const int* tg = targets + b * L;

  // skip-allowed multipliers for odd states (1.0f or 0.0f)
  float f1 = 0.0f, f3, f5, f7 = 0.0f;
  {
    int s = s0 + 1;
    if (s >= 3) f1 = (tg[(s + 1) >> 1] != tg[(s - 1) >> 1]) ? 1.0f : 0.0f;
    s = s0 + 3;
    f3 = (tg[(s + 1) >> 1] != tg[(s - 1) >> 1]) ? 1.0f : 0.0f;
    s = s0 + 5;
    f5 = (tg[(s + 1) >> 1] != tg[(s - 1) >> 1]) ? 1.0f : 0.0f;
    s = s0 + 7;
    if (s < S) f7 = (tg[(s + 1) >> 1] != tg[(s - 1) >> 1]) ? 1.0f : 0.0f;
  }

  const float* E0 = E + (size_t)b * TP * SP;
  const float4* Ep = reinterpret_cast<const float4*>(E0 + s0);  // row r: Ep[r*128], Ep[r*128+1]

  // alpha init from t=0: only s=0,1 live
  float a0 = (lane == 0) ? E0[0] : 0.0f;
  float a1 = (lane == 0) ? E0[1] : 0.0f;
  float a2 = 0.f, a3 = 0.f, a4 = 0.f, a5 = 0.f, a6 = 0.f, a7 = 0.f;
  float n7 = 0.0f;  // a7 of lane-1, pipelined across steps
  int lsacc = 0;

// One time step. t7 first, its DPP issued immediately (result used next step).
#define STEPF(EL, EH)                                           \
  do {                                                          \
    float t7 = fmaf(f7, a5, a6 + a7) * (EH).w;                  \
    float n7n = shr1f(t7);                                      \
    float t0 = (a0 + n7) * (EL).x;                              \
    float t1 = fmaf(f1, n7, a0 + a1) * (EL).y;                  \
    float t2 = (a1 + a2) * (EL).z;                              \
    float t3 = fmaf(f3, a1, a2 + a3) * (EL).w;                  \
    float t4 = (a3 + a4) * (EH).x;                              \
    float t5 = fmaf(f5, a3, a4 + a5) * (EH).y;                  \
    float t6 = (a5 + a6) * (EH).z;                              \
    a0 = t0; a1 = t1; a2 = t2; a3 = t3;                         \
    a4 = t4; a5 = t5; a6 = t6; a7 = t7;                         \
    n7 = n7n;                                                   \
  } while (0)

#define LOAD8(P, r0)                                            \
  do {                                                          \
    const float4* q = Ep + (size_t)(r0) * 128;                  \
    P##0a = q[0];   P##0b = q[1];                               \
    P##1a = q[128]; P##1b = q[129];                             \
    P##2a = q[256]; P##2b = q[257];                             \
    P##3a = q[384]; P##3b = q[385];                             \
    P##4a = q[512]; P##4b = q[513];                             \
    P##5a = q[640]; P##5b = q[641];                             \
    P##6a = q[768]; P##6b = q[769];                             \
    P##7a = q[896]; P##7b = q[897];                             \
  } while (0)

// exact pow2 rescale: wave-max alpha -> 2^102.
// Growth bound: alphas multiply by E<=1 and sum <=3 terms -> max grows
// <= 3^8 ~ 2^12.7 per 8 steps; 2^102 * 2^13 << 2^127 (no overflow).
// Underflow window: 102+149 = 251 log2 (~174 nats) below the max.
#define RESCALE()                                               \
  do {                                                          \
    int m = max(max(max(__float_as_int(a0), __float_as_int(a1)),\
                    max(__float_as_int(a2), __float_as_int(a3))),\
                max(max(__float_as_int(a4), __float_as_int(a5)),\
                    max(__float_as_int(a6), __float_as_int(a7))));\
    int mw = wavemax_to_sgpr(m);                                \
    int e = mw >> 23;                                           \
    int sh = 229 - e;                                           \
    lsacc += e - 229;                                           \
    a0 = ldexpf(a0, sh); a1 = ldexpf(a1, sh);                   \
    a2 = ldexpf(a2, sh); a3 = ldexpf(a3, sh);                   \
    a4 = ldexpf(a4, sh); a5 = ldexpf(a5, sh);                   \
    a6 = ldexpf(a6, sh); a7 = ldexpf(a7, sh);                   \
    n7 = ldexpf(n7, sh);                                        \
  } while (0)

#define PROC8R(P)                                               \
  do {                                                          \
    RESCALE();                                                  \
    STEPF(P##0a, P##0b); STEPF(P##1a, P##1b);                   \
    STEPF(P##2a, P##2b); STEPF(P##3a, P##3b);                   \
    STEPF(P##4a, P##4b); STEPF(P##5a, P##5b);                   \
    STEPF(P##6a, P##6b); STEPF(P##7a, P##7b);                   \
  } while (0)

  float4 A0a, A0b, A1a, A1b, A2a, A2b, A3a, A3b;
  float4 A4a, A4b, A5a, A5b, A6a, A6b, A7a, A7b;
  float4 B0a, B0b, B1a, B1b, B2a, B2b, B3a, B3b;
  float4 B4a, B4b, B5a, B5b, B6a, B6b, B7a, B7b;
  float4 C0a, C0b, C1a, C1b, C2a, C2b, C3a, C3b;
  float4 C4a, C4b, C5a, C5b, C6a, C6b, C7a, C7b;
  float4 D0a, D0b, D1a, D1b, D2a, D2b, D3a, D3b;
  float4 D4a, D4b, D5a, D5b, D6a, D6b, D7a, D7b;

  LOAD8(A, 1);    // rows 1..8
  LOAD8(B, 9);    // rows 9..16
  LOAD8(C, 17);   // rows 17..24
  LOAD8(D, 25);   // rows 25..32

  int t = 1;
#pragma unroll 1
  for (int it = 0; it < 31; ++it) {  // 31*32 = 992 rows
    PROC8R(A); LOAD8(A, t + 32);
    PROC8R(B); LOAD8(B, t + 40);
    PROC8R(C); LOAD8(C, t + 48);
    PROC8R(D); LOAD8(D, t + 56);
    t += 32;
  }
  // t = 993: A=993..1000, B=1001..1008, C=1009..1016, D=1017..1024
  PROC8R(A);
  PROC8R(B);
  PROC8R(C);
  RESCALE();
  STEPF(D0a, D0b); STEPF(D1a, D1b); STEPF(D2a, D2b);
  STEPF(D3a, D3b); STEPF(D4a, D4b); STEPF(D5a, D5b);  // rows 1017..1022
#undef STEPF
#undef LOAD8
#undef PROC8R
#undef RESCALE

  __shared__ float sal[SP];
  sal[s0 + 0] = a0; sal[s0 + 1] = a1; sal[s0 + 2] = a2; sal[s0 + 3] = a3;
  sal[s0 + 4] = a4; sal[s0 + 5] = a5; sal[s0 + 6] = a6; sal[s0 + 7] = a7;
  __syncthreads();
  if (lane == 0) {
    int tl = tlenp[b];
    int i1 = 2 * tl;
    float p = sal[i1] + sal[(i1 > 0 ? i1 : 1) - 1];
    int hi = __float_as_int(p);
    int ep = (hi >> 23) - 127;
    float pm = ldexpf(p, -ep);          // in [1,2) for normal p
    float lm = flog2(pm);
    double loss2 = -((double)lm + (double)ep + (double)lsacc + GS[b]);
    float loss = (float)(loss2 * LN2);  // back to natural log
    if (!(loss <= 1e20f)) loss = 0.0f;  // zero_infinity (inf/nan -> 0)
    int dv = (tl > 0) ? tl : 1;
    lossb[b] = loss / (float)dv;
  }
}

// ---------------- K3: deterministic mean ---------------------------------
__global__ void k_mean(const float* __restrict__ lossb, float* __restrict__ out) {
  int lane = threadIdx.x;
  float v = (lane < B) ? lossb[lane] : 0.0f;
  for (int o = 32; o >= 1; o >>= 1) v += __shfl_xor(v, o, 64);
  if (lane == 0) out[0] = v / (float)B;
}

extern "C" void kernel_launch(void* const* d_in, const int* in_sizes, int n_in,
                              void* d_out, int out_size, void* d_ws, size_t ws_size,
                              hipStream_t stream) {
  const float* logits = (const float*)d_in[0];
  const int* targets = (const int*)d_in[1];
  const unsigned char* mask = (const unsigned char*)d_in[2];

  char* ws = (char*)d_ws;
  int* tlen = (int*)ws;                  // [0,128)
  float* lossb = (float*)(ws + 128);     // [128,256)
  double* GS = (double*)(ws + 256);      // [256,512)
  float* G = (float*)(ws + 512);         // 32*1023 f32 = 131KB
  float* E = (float*)(ws + 512 + 132 * 1024);  // 32*1024*512 f32 = 64MB
  // note: k_ctc's deepest prefetch touches row 1024 of batch 31 (2KB past E);
  // ws is far larger than E+slack, so reads stay in-bounds of d_ws.

  k_tlen<<<B, 64, 0, stream>>>(mask, tlen);
  k_emit<<<B * TT, 256, 0, stream>>>(logits, targets, tlen, E, G);
  k_gsum<<<B, 64, 0, stream>>>(G, GS);
  k_ctc<<<B, 64, 0, stream>>>(E, targets, tlen, GS, lossb);
  k_mean<<<1, 64, 0, stream>>>(lossb, (float*)d_out);
}

// Round 6
// 104.330 us; speedup vs baseline: 1.4144x; 1.4144x over previous
//
#include <hip/hip_runtime.h>

#define LOG2E 1.4426950408889634f
#define LN2   0.6931471805599453

static constexpr int B  = 32;
static constexpr int T  = 1024;   // original time length; we use rows 0..1022
static constexpr int TT = 1023;   // T-1
static constexpr int V  = 1000;
static constexpr int L  = 256;    // padded target length; labels used are cols 1..255
static constexpr int S  = 511;    // 2*255+1 extended states (valid s: 0..510)
static constexpr int SP = 512;    // padded state stride (slot 511 == 0.0f)
static constexpr int TP = 1024;   // padded rows per batch in E

using f4 = __attribute__((ext_vector_type(4))) float;

__device__ __forceinline__ float fexp2(float x) {
#if __has_builtin(__builtin_amdgcn_exp2f)
  return __builtin_amdgcn_exp2f(x);
#else
  return exp2f(x);
#endif
}
__device__ __forceinline__ float flog2(float x) {
#if __has_builtin(__builtin_amdgcn_logf)
  return __builtin_amdgcn_logf(x);   // v_log_f32 = log base 2
#else
  return log2f(x);
#endif
}

// ---- DPP helpers (VALU cross-lane; no LDS) ------------------------------
#if __has_builtin(__builtin_amdgcn_update_dpp)
// wave_shr1: lane i <- lane i-1; lane 0 <- 0 (bound_ctrl)
__device__ __forceinline__ float shr1f(float x) {
  int r = __builtin_amdgcn_update_dpp(0, __float_as_int(x), 0x138, 0xf, 0xf, true);
  return __int_as_float(r);
}
__device__ __forceinline__ int dppmax_step(int m, const int ctrl) {
  int t;
  switch (ctrl) {
    case 0x111: t = __builtin_amdgcn_update_dpp(0, m, 0x111, 0xf, 0xf, true); break;
    case 0x112: t = __builtin_amdgcn_update_dpp(0, m, 0x112, 0xf, 0xf, true); break;
    case 0x114: t = __builtin_amdgcn_update_dpp(0, m, 0x114, 0xf, 0xf, true); break;
    case 0x118: t = __builtin_amdgcn_update_dpp(0, m, 0x118, 0xf, 0xf, true); break;
    case 0x142: t = __builtin_amdgcn_update_dpp(0, m, 0x142, 0xf, 0xf, true); break;
    default:    t = __builtin_amdgcn_update_dpp(0, m, 0x143, 0xf, 0xf, true); break;
  }
  return max(m, t);
}
// wave-max of nonneg int across 64 lanes
__device__ __forceinline__ int wavemax_to_sgpr(int m) {
  m = dppmax_step(m, 0x111);  // row_shr:1
  m = dppmax_step(m, 0x112);  // row_shr:2
  m = dppmax_step(m, 0x114);  // row_shr:4
  m = dppmax_step(m, 0x118);  // row_shr:8
  m = dppmax_step(m, 0x142);  // row_bcast15
  m = dppmax_step(m, 0x143);  // row_bcast31
  return __builtin_amdgcn_readlane(m, 63);
}
#else
__device__ __forceinline__ float shr1f(float x) {
  float r = __shfl_up(x, 1, 64);
  return (threadIdx.x & 63) == 0 ? 0.0f : r;
}
__device__ __forceinline__ int wavemax_to_sgpr(int m) {
  for (int o = 32; o >= 1; o >>= 1) m = max(m, __shfl_xor(m, o, 64));
  return m;
}
#endif

// ---------------- K0: target lengths from padding mask -------------------
__global__ void k_tlen(const unsigned char* __restrict__ maskb,
                       int* __restrict__ tlen) {
  int b = blockIdx.x;
  int lane = threadIdx.x;
  int ca = 0;
  for (int k = lane; k < L; k += 64) ca += (maskb[b * L + k] != 0) ? 1 : 0;
  for (int o = 32; o >= 1; o >>= 1) ca += __shfl_xor(ca, o, 64);
  int cnt = ca;
  if (ca < 130) {  // wave-uniform: layout must be int32
    const int* mi = (const int*)maskb;
    int cb = 0;
    for (int k = lane; k < L; k += 64) cb += (mi[b * L + k] != 0) ? 1 : 0;
    for (int o = 32; o >= 1; o >>= 1) cb += __shfl_xor(cb, o, 64);
    cnt = cb;
  }
  if (lane == 0) tlen[b] = cnt - 1;
}

// ---------------- K1: fused softmax-scale + emit gather ------------------
// E[b][t][s] = 2^(y[ext_s] - rowmax) in f32 (<=1), 0 for invalid; slot 511 = 0.
// G[b][t] = rowmax - log2(sum 2^(y-rowmax)).
__global__ __launch_bounds__(256) void k_emit(const float* __restrict__ logits,
                                              const int* __restrict__ targets,
                                              const int* __restrict__ tlenp,
                                              float* __restrict__ E,
                                              float* __restrict__ G) {
  __shared__ float yrow[1000];
  __shared__ float smx[4];
  __shared__ float ssm[4];
  int bid = blockIdx.x;
  int b = bid / TT;
  int t = bid - b * TT;
  int tid = threadIdx.x;

  const float4* row = reinterpret_cast<const float4*>(logits + ((size_t)b * T + t) * V);
  float4 vv = make_float4(0.f, 0.f, 0.f, 0.f);
  float vmax = -3.402823466e38f;
  if (tid < 250) {  // 1000 = 250 * 4 exactly
    vv = row[tid];
    vv.x *= LOG2E; vv.y *= LOG2E; vv.z *= LOG2E; vv.w *= LOG2E;
    yrow[4 * tid + 0] = vv.x;
    yrow[4 * tid + 1] = vv.y;
    yrow[4 * tid + 2] = vv.z;
    yrow[4 * tid + 3] = vv.w;
    vmax = fmaxf(fmaxf(vv.x, vv.y), fmaxf(vv.z, vv.w));
  }
  for (int o = 32; o >= 1; o >>= 1) vmax = fmaxf(vmax, __shfl_xor(vmax, o, 64));
  int wid = tid >> 6;
  if ((tid & 63) == 0) smx[wid] = vmax;
  __syncthreads();
  float my = fmaxf(fmaxf(smx[0], smx[1]), fmaxf(smx[2], smx[3]));
  float ps = 0.0f;
  if (tid < 250) {
    ps = fexp2(vv.x - my) + fexp2(vv.y - my) + fexp2(vv.z - my) + fexp2(vv.w - my);
  }
  for (int o = 32; o >= 1; o >>= 1) ps += __shfl_xor(ps, o, 64);
  if ((tid & 63) == 0) ssm[wid] = ps;
  __syncthreads();
  float g = -flog2(ssm[0] + ssm[1] + ssm[2] + ssm[3]);  // = rowmax - lse2

  int tl = tlenp[b];
  int smax = 2 * tl + 1;  // valid: s < smax
  float* Erow = E + ((size_t)b * TP + t) * SP;
  if (tid < 128) {
    int s4 = tid << 2;               // s4, s4+1, s4+2, s4+3
    float eblank = fexp2(yrow[0] - my);
    int idx1 = (tid << 1) + 1;       // label index for s4+1
    int idx3 = (tid << 1) + 2;       // label index for s4+3
    bool last = (tid == 127);        // s4+3 == 511 (pad slot)
    if (last) idx3 = 0;              // keep targets access in-bounds
    float v1c = fexp2(yrow[targets[b * L + idx1]] - my);
    float v3c = fexp2(yrow[targets[b * L + idx3]] - my);
    float4 o;
    o.x = (s4     < smax) ? eblank : 0.0f;
    o.y = (s4 + 1 < smax) ? v1c    : 0.0f;
    o.z = (s4 + 2 < smax) ? eblank : 0.0f;
    o.w = (!last && (s4 + 3 < smax)) ? v3c : 0.0f;  // slot 511 -> 0
    reinterpret_cast<float4*>(Erow)[tid] = o;
    if (last) G[b * TT + t] = g;
  }
}

// ---------------- K1b: per-batch sum of G --------------------------------
__global__ void k_gsum(const float* __restrict__ G, double* __restrict__ GS) {
  int b = blockIdx.x;
  int lane = threadIdx.x;
  double s = 0.0;
  for (int k = lane; k < TT; k += 64) s += (double)G[b * TT + k];
  for (int o = 32; o >= 1; o >>= 1) s += __shfl_xor(s, o, 64);
  if (lane == 0) GS[b] = s;
}

// ---------------- K2: CTC alpha recurrence, f32 prob domain --------------
// One wave per batch; lane l owns states 8l..8l+7. Inline-asm load pipeline:
// 3 buffers x 8 rows, issued with asm global_load_dwordx4 (cannot be sunk),
// consumed behind counted s_waitcnt vmcnt(32) that REDEFINES the buffer regs
// ("+v") so no use/copy can precede the wait. Peak 48 outstanding loads.
__global__ __launch_bounds__(64, 1) void k_ctc(const float* __restrict__ E,
                                               const int* __restrict__ targets,
                                               const int* __restrict__ tlenp,
                                               const double* __restrict__ GS,
                                               float* __restrict__ lossb) {
  const int b = blockIdx.x;
  const int lane = threadIdx.x;
  const int s0 = lane << 3;
  const int* tg = targets + b * L;

  // skip-allowed multipliers for odd states (1.0f or 0.0f)
  float f1 = 0.0f, f3, f5, f7 = 0.0f;
  {
    int s = s0 + 1;
    if (s >= 3) f1 = (tg[(s + 1) >> 1] != tg[(s - 1) >> 1]) ? 1.0f : 0.0f;
    s = s0 + 3;
    f3 = (tg[(s + 1) >> 1] != tg[(s - 1) >> 1]) ? 1.0f : 0.0f;
    s = s0 + 5;
    f5 = (tg[(s + 1) >> 1] != tg[(s - 1) >> 1]) ? 1.0f : 0.0f;
    s = s0 + 7;
    if (s < S) f7 = (tg[(s + 1) >> 1] != tg[(s - 1) >> 1]) ? 1.0f : 0.0f;
  }

  const float* E0 = E + (size_t)b * TP * SP;
  const float* Ebase = E0 + s0;   // row r starts at Ebase + r*SP (per-lane)

  // alpha init from t=0: only s=0,1 live
  float a0 = (lane == 0) ? E0[0] : 0.0f;
  float a1 = (lane == 0) ? E0[1] : 0.0f;
  float a2 = 0.f, a3 = 0.f, a4 = 0.f, a5 = 0.f, a6 = 0.f, a7 = 0.f;
  float n7 = 0.0f;  // a7 of lane-1, pipelined across steps
  int lsacc = 0;

  // Force all compiler-issued loads (tg flags, E0[0..1]) to complete NOW so
  // the compiler never inserts its own s_waitcnt vmcnt(0) inside the loop.
  asm volatile("" :: "v"(f1), "v"(f3), "v"(f5), "v"(f7), "v"(a0), "v"(a1));

// two dwordx4 loads for one row (32 floats of this lane's 8-state slice? no:
// 8 floats = 2 x float4 per row), via asm so they cannot be sunk.
#define GL16(d0, d1, p)                                          \
  asm volatile("global_load_dwordx4 %0, %2, off\n\t"             \
               "global_load_dwordx4 %1, %2, off offset:16"       \
               : "=&v"(d0), "=&v"(d1) : "v"(p))

#define LOAD8(P, r0)                                             \
  do {                                                           \
    const float* q_ = Ebase + (size_t)(r0) * SP;                 \
    GL16(P##0a, P##0b, q_);                                      \
    GL16(P##1a, P##1b, q_ + SP);                                 \
    GL16(P##2a, P##2b, q_ + 2 * SP);                             \
    GL16(P##3a, P##3b, q_ + 3 * SP);                             \
    GL16(P##4a, P##4b, q_ + 4 * SP);                             \
    GL16(P##5a, P##5b, q_ + 5 * SP);                             \
    GL16(P##6a, P##6b, q_ + 6 * SP);                             \
    GL16(P##7a, P##7b, q_ + 7 * SP);                             \
  } while (0)

// counted wait; redefines buffer P's registers so uses can't precede it
#define VMWAIT16(n, P)                                           \
  do {                                                           \
    asm volatile("s_waitcnt vmcnt(" #n ")"                       \
                 : "+v"(P##0a), "+v"(P##0b), "+v"(P##1a), "+v"(P##1b), \
                   "+v"(P##2a), "+v"(P##2b), "+v"(P##3a), "+v"(P##3b)); \
    asm volatile(""                                              \
                 : "+v"(P##4a), "+v"(P##4b), "+v"(P##5a), "+v"(P##5b), \
                   "+v"(P##6a), "+v"(P##6b), "+v"(P##7a), "+v"(P##7b)); \
    __builtin_amdgcn_sched_barrier(0);                           \
  } while (0)

// One time step. t7 first, its DPP issued immediately (result used next step).
#define STEPF(EL, EH)                                           \
  do {                                                          \
    float t7 = fmaf(f7, a5, a6 + a7) * (EH).w;                  \
    float n7n = shr1f(t7);                                      \
    float t0 = (a0 + n7) * (EL).x;                              \
    float t1 = fmaf(f1, n7, a0 + a1) * (EL).y;                  \
    float t2 = (a1 + a2) * (EL).z;                              \
    float t3 = fmaf(f3, a1, a2 + a3) * (EL).w;                  \
    float t4 = (a3 + a4) * (EH).x;                              \
    float t5 = fmaf(f5, a3, a4 + a5) * (EH).y;                  \
    float t6 = (a5 + a6) * (EH).z;                              \
    a0 = t0; a1 = t1; a2 = t2; a3 = t3;                         \
    a4 = t4; a5 = t5; a6 = t6; a7 = t7;                         \
    n7 = n7n;                                                   \
  } while (0)

// exact pow2 rescale: wave-max alpha -> 2^102.
// Growth <= 3^8 ~ 2^12.7 per 8 steps; 2^102 * 2^13 << 2^127 (no overflow).
// Underflow window: 102+149 = 251 log2 (~174 nats) below the max.
#define RESCALE()                                               \
  do {                                                          \
    int m = max(max(max(__float_as_int(a0), __float_as_int(a1)),\
                    max(__float_as_int(a2), __float_as_int(a3))),\
                max(max(__float_as_int(a4), __float_as_int(a5)),\
                    max(__float_as_int(a6), __float_as_int(a7))));\
    int mw = wavemax_to_sgpr(m);                                \
    int e = mw >> 23;                                           \
    int sh = 229 - e;                                           \
    lsacc += e - 229;                                           \
    a0 = ldexpf(a0, sh); a1 = ldexpf(a1, sh);                   \
    a2 = ldexpf(a2, sh); a3 = ldexpf(a3, sh);                   \
    a4 = ldexpf(a4, sh); a5 = ldexpf(a5, sh);                   \
    a6 = ldexpf(a6, sh); a7 = ldexpf(a7, sh);                   \
    n7 = ldexpf(n7, sh);                                        \
  } while (0)

#define PROC8R(P)                                               \
  do {                                                          \
    RESCALE();                                                  \
    STEPF(P##0a, P##0b); STEPF(P##1a, P##1b);                   \
    STEPF(P##2a, P##2b); STEPF(P##3a, P##3b);                   \
    STEPF(P##4a, P##4b); STEPF(P##5a, P##5b);                   \
    STEPF(P##6a, P##6b); STEPF(P##7a, P##7b);                   \
  } while (0)

  f4 A0a, A0b, A1a, A1b, A2a, A2b, A3a, A3b;
  f4 A4a, A4b, A5a, A5b, A6a, A6b, A7a, A7b;
  f4 B0a, B0b, B1a, B1b, B2a, B2b, B3a, B3b;
  f4 B4a, B4b, B5a, B5b, B6a, B6b, B7a, B7b;
  f4 C0a, C0b, C1a, C1b, C2a, C2b, C3a, C3b;
  f4 C4a, C4b, C5a, C5b, C6a, C6b, C7a, C7b;

  LOAD8(A, 1);    // rows 1..8     (16 loads)
  LOAD8(B, 9);    // rows 9..16    (32)
  LOAD8(C, 17);   // rows 17..24   (48 outstanding)

  int t = 1;
#pragma unroll 1
  for (int it = 0; it < 41; ++it) {   // 41 * 24 = 984 rows: t = 1 .. 984
    VMWAIT16(32, A); PROC8R(A); LOAD8(A, t + 24);
    VMWAIT16(32, B); PROC8R(B); LOAD8(B, t + 32);
    VMWAIT16(32, C); PROC8R(C); LOAD8(C, t + 40);
    t += 24;
  }
  // t = 985. In flight: A=985..992, B=993..1000, C=1001..1008 (48 loads).
  VMWAIT16(32, A); PROC8R(A); LOAD8(A, 1009);   // rows 985..992; load 1009..1016
  VMWAIT16(32, B); PROC8R(B); LOAD8(B, 1017);   // rows 993..1000; load 1017..1024
  VMWAIT16(32, C); PROC8R(C);                   // rows 1001..1008
  VMWAIT16(16, A); PROC8R(A);                   // rows 1009..1016
  VMWAIT16(0, B);                               // rows 1017..1022 (last 6)
  RESCALE();
  STEPF(B0a, B0b); STEPF(B1a, B1b); STEPF(B2a, B2b);
  STEPF(B3a, B3b); STEPF(B4a, B4b); STEPF(B5a, B5b);
#undef GL16
#undef LOAD8
#undef VMWAIT16
#undef STEPF
#undef RESCALE
#undef PROC8R

  __shared__ float sal[SP];
  sal[s0 + 0] = a0; sal[s0 + 1] = a1; sal[s0 + 2] = a2; sal[s0 + 3] = a3;
  sal[s0 + 4] = a4; sal[s0 + 5] = a5; sal[s0 + 6] = a6; sal[s0 + 7] = a7;
  __syncthreads();
  if (lane == 0) {
    int tl = tlenp[b];
    int i1 = 2 * tl;
    float p = sal[i1] + sal[(i1 > 0 ? i1 : 1) - 1];
    int hi = __float_as_int(p);
    int ep = (hi >> 23) - 127;
    float pm = ldexpf(p, -ep);          // in [1,2) for normal p
    float lm = flog2(pm);
    double loss2 = -((double)lm + (double)ep + (double)lsacc + GS[b]);
    float loss = (float)(loss2 * LN2);  // back to natural log
    if (!(loss <= 1e20f)) loss = 0.0f;  // zero_infinity (inf/nan -> 0)
    int dv = (tl > 0) ? tl : 1;
    lossb[b] = loss / (float)dv;
  }
}

// ---------------- K3: deterministic mean ---------------------------------
__global__ void k_mean(const float* __restrict__ lossb, float* __restrict__ out) {
  int lane = threadIdx.x;
  float v = (lane < B) ? lossb[lane] : 0.0f;
  for (int o = 32; o >= 1; o >>= 1) v += __shfl_xor(v, o, 64);
  if (lane == 0) out[0] = v / (float)B;
}

extern "C" void kernel_launch(void* const* d_in, const int* in_sizes, int n_in,
                              void* d_out, int out_size, void* d_ws, size_t ws_size,
                              hipStream_t stream) {
  const float* logits = (const float*)d_in[0];
  const int* targets = (const int*)d_in[1];
  const unsigned char* mask = (const unsigned char*)d_in[2];

  char* ws = (char*)d_ws;
  int* tlen = (int*)ws;                  // [0,128)
  float* lossb = (float*)(ws + 128);     // [128,256)
  double* GS = (double*)(ws + 256);      // [256,512)
  float* G = (float*)(ws + 512);         // 32*1023 f32 = 131KB
  float* E = (float*)(ws + 512 + 132 * 1024);  // 32*1024*512 f32 = 64MB
  // k_ctc's deepest prefetch touches row 1024 of batch 31 (2KB past E);
  // ws (512MB) is far larger than E+slack, so those reads stay in-bounds.

  k_tlen<<<B, 64, 0, stream>>>(mask, tlen);
  k_emit<<<B * TT, 256, 0, stream>>>(logits, targets, tlen, E, G);
  k_gsum<<<B, 64, 0, stream>>>(G, GS);
  k_ctc<<<B, 64, 0, stream>>>(E, targets, tlen, GS, lossb);
  k_mean<<<1, 64, 0, stream>>>(lossb, (float*)d_out);
}